// Round 13
// baseline (68.427 us; speedup 1.0000x reference)
//
#include <hip/hip_runtime.h>
#include <hip/hip_bf16.h>
#include <stdint.h>

// MultiHead attention: B=2, S=2048, D=512, H=8, dh=64. f32 I/O, bf16 MFMA core.
// NOTE: reference projects q,k,v ALL with Wq (faithful to original bug).
// v13 = v12 with the attn iteration REORDERED:
//   [vmcnt(4)+barrier] -> stage(t+3) -> QK(t+1) -> exp2/pack(t) -> PV(t)
// Barrier arrives right after PV(t-1) (not after the exp2 chain), and
// QK(t+1) MFMA executes under exp2(t) VALU (dual-pipe overlap). Buffer/
// vmcnt guarantees identical to v12 (audited; t=14 uses vmcnt(0)).

typedef __bf16 bf16;
typedef __bf16 bvec8 __attribute__((ext_vector_type(8)));
typedef __bf16 bvec4 __attribute__((ext_vector_type(4)));
typedef float  fvec4 __attribute__((ext_vector_type(4)));
typedef float  fvec16 __attribute__((ext_vector_type(16)));
typedef int    ivec4 __attribute__((ext_vector_type(4)));

#define MFMA16(a, b, c) __builtin_amdgcn_mfma_f32_16x16x32_bf16(a, b, c, 0, 0, 0)
#define MFMA32(a, b, c) __builtin_amdgcn_mfma_f32_32x32x16_bf16(a, b, c, 0, 0, 0)

// async global->LDS, 16B per lane. HW: wave-uniform LDS base + lane*16.
__device__ __forceinline__ void async16(const void* g, void* l) {
  __builtin_amdgcn_global_load_lds(
      (__attribute__((address_space(1))) void*)(g),
      (__attribute__((address_space(3))) void*)(l), 16, 0, 0);
}

// ---------------------------------------------------------------------------
// All f32->bf16 conversions in ONE launch: q,k,v -> qkvb[3][4096][512],
// Wq -> Wq16, Wc -> Wc16. 8 elems/thread.
// ---------------------------------------------------------------------------
__global__ void cvt_all(const float* __restrict__ q, const float* __restrict__ k,
                        const float* __restrict__ v, const float* __restrict__ Wq,
                        const float* __restrict__ Wc, bf16* __restrict__ qkvb,
                        bf16* __restrict__ Wq16, bf16* __restrict__ Wc16) {
  const int t = blockIdx.x * 256 + threadIdx.x;
  const float* src;
  bf16* dst;
  size_t i;
  if (t < 786432) {                       // 3 * 2^18 threads for q,k,v
    const int which = t >> 18;
    i = (size_t)(t & 262143);
    src = (which == 0) ? q : (which == 1) ? k : v;
    dst = qkvb + ((size_t)which << 21);   // 2^21 elems per tensor
  } else if (t < 819200) {
    src = Wq; dst = Wq16; i = (size_t)(t - 786432);
  } else {
    src = Wc; dst = Wc16; i = (size_t)(t - 819200);
  }
  fvec4 a = *(const fvec4*)(src + i * 8);
  fvec4 b = *(const fvec4*)(src + i * 8 + 4);
  bvec8 o;
#pragma unroll
  for (int j = 0; j < 4; ++j) { o[j] = (bf16)a[j]; o[j + 4] = (bf16)b[j]; }
  *(bvec8*)(dst + i * 8) = o;
}

// ---------------------------------------------------------------------------
// Projection GEMM: Y[12288,512] = X @ Wq^T + bias (bf16 in, fp32 acc).
// BM=64, BN=128, BK=64; 256 threads (2x2 waves, wave tile 32x64).
// LDS XOR swizzle (16B chunk g of row r at pos g^(r&7); inverse on DMA src).
// Rows < 4096 (q third): result scaled by SC=log2(e)/8 before bf16 round.
// Rows >= 8192 (v third): store transposed per-head into Yt.
// ---------------------------------------------------------------------------
__launch_bounds__(256, 3)
__global__ void proj_gemm(const bf16* __restrict__ X, const bf16* __restrict__ W,
                          const float* __restrict__ bias, bf16* __restrict__ Y,
                          bf16* __restrict__ Yt) {
  __shared__ __attribute__((aligned(16))) char As[2][64 * 128];   // 8 KB each
  __shared__ __attribute__((aligned(16))) char Bs[2][128 * 128];  // 16 KB each

  const int tid = threadIdx.x;
  const int w = tid >> 6, l = tid & 63;
  const int wr = w >> 1, wc = w & 1;
  const int l15 = l & 15, lg = l >> 4;
  const int bm0 = blockIdx.x * 64;
  const int bn0 = blockIdx.y * 128;

  fvec4 acc[2][4] = {};

  auto stageA = [&](int buf, int k0) {
#pragma unroll
    for (int j = 0; j < 2; ++j) {
      int c = j * 256 + tid;
      int row = c >> 3, g = (c & 7) ^ (row & 7);
      async16(X + (size_t)(bm0 + row) * 512 + k0 + g * 8, &As[buf][c * 16]);
    }
  };
  auto stageB = [&](int buf, int k0) {
#pragma unroll
    for (int j = 0; j < 4; ++j) {
      int c = j * 256 + tid;
      int row = c >> 3, g = (c & 7) ^ (row & 7);
      async16(W + (size_t)(bn0 + row) * 512 + k0 + g * 8, &Bs[buf][c * 16]);
    }
  };

  stageA(0, 0);
  stageB(0, 0);
  __syncthreads();

  for (int t = 0; t < 8; ++t) {
    const int buf = t & 1;
    if (t < 7) { stageA(buf ^ 1, (t + 1) * 64); stageB(buf ^ 1, (t + 1) * 64); }
#pragma unroll
    for (int kk = 0; kk < 2; ++kk) {
      bvec8 af[2], bfr[4];
      const int g = kk * 4 + lg;
#pragma unroll
      for (int m = 0; m < 2; ++m) {
        int r = wr * 32 + m * 16 + l15;
        af[m] = *(const bvec8*)&As[buf][r * 128 + ((g ^ (r & 7)) << 4)];
      }
#pragma unroll
      for (int n = 0; n < 4; ++n) {
        int r = wc * 64 + n * 16 + l15;
        bfr[n] = *(const bvec8*)&Bs[buf][r * 128 + ((g ^ (r & 7)) << 4)];
      }
#pragma unroll
      for (int m = 0; m < 2; ++m)
#pragma unroll
        for (int n = 0; n < 4; ++n) acc[m][n] = MFMA16(af[m], bfr[n], acc[m][n]);
    }
    __syncthreads();
  }

  // Epilogue. C layout: col = lane&15, rows = (lane>>4)*4 + r.
  const bool trans = (bm0 >= 8192);
  const float scl = (bm0 < 4096) ? 0.18033688011112042f : 1.0f;  // log2(e)/8
#pragma unroll
  for (int n = 0; n < 4; ++n) {
    const int col = bn0 + wc * 64 + n * 16 + l15;
    const float bv = bias[col];
#pragma unroll
    for (int m = 0; m < 2; ++m) {
      const int row0 = bm0 + wr * 32 + m * 16 + lg * 4;
      if (!trans) {
#pragma unroll
        for (int r = 0; r < 4; ++r)
          Y[(size_t)(row0 + r) * 512 + col] = (bf16)((acc[m][n][r] + bv) * scl);
      } else {
        const int m0 = row0 - 8192;
        const int b = m0 >> 11, s = m0 & 2047;
        bvec4 v4;
#pragma unroll
        for (int r = 0; r < 4; ++r) v4[r] = (bf16)(acc[m][n][r] + bv);
        *(bvec4*)&Yt[(size_t)(b * 512 + col) * 2048 + s] = v4;
      }
    }
  }
}

// ---------------------------------------------------------------------------
// Flash attention v13. Grid (16 qb, 16 bh, 2 kv-halves) = 512 blocks,
// 2 blocks/CU. 16 tiles/block. Iteration order:
//   [vmcnt(4)+barrier] -> stage(t+3) -> QK(t+1) -> exp2/pack(t) -> PV(t)
// 4 LDS buffers (64 KB); stages t+2 (and t+3 after issue) in flight across
// barriers. Swapped QK^T (Q pre-scaled log2(e)/8) -> p=exp2(s) lane-local;
// P via v_cvt_pk_bf16_f32 + permlane32_swap; PV + ones-MFMA row sums.
// ---------------------------------------------------------------------------
__launch_bounds__(256, 2)
__global__ void attn_kernel(const bf16* __restrict__ qp, const bf16* __restrict__ kp,
                            const bf16* __restrict__ vt, bf16* __restrict__ po,
                            float* __restrict__ pl) {
  __shared__ __attribute__((aligned(16))) char Ks[4][64 * 128];  // 8 KB each
  __shared__ __attribute__((aligned(16))) char Vs[4][64 * 128];

  const int tid = threadIdx.x;
  const int w = tid >> 6, l = tid & 63;
  const int l31 = l & 31, hi = l >> 5;
  const int bh = blockIdx.y, b = bh >> 3, h = bh & 7;
  const int half = blockIdx.z;
  const int kvbase = half * 1024;
  const int qw0 = blockIdx.x * 128 + w * 32;

  const bf16* kbase = kp + (size_t)(b * 2048) * 512 + h * 64;
  const bf16* vbase = vt + (size_t)(b * 512 + h * 64) * 2048;

  bvec8 qf[4];
  {
    const bf16* qrow = qp + (size_t)(b * 2048 + qw0 + l31) * 512 + h * 64 + hi * 8;
#pragma unroll
    for (int ks = 0; ks < 4; ++ks) qf[ks] = *(const bvec8*)(qrow + ks * 16);
  }
  bvec8 ones;
#pragma unroll
  for (int e = 0; e < 8; ++e) ones[e] = (bf16)1.0f;

  // one stage = 2 K-loads + 2 V-loads per thread (vmcnt 4/stage/wave)
  auto stage = [&](int buf, int kv0) {
#pragma unroll
    for (int j = 0; j < 2; ++j) {
      int c = j * 256 + tid;
      int row = c >> 3, g = (c & 7) ^ (row & 7);
      async16(kbase + (size_t)(kv0 + row) * 512 + g * 8, &Ks[buf][c * 16]);
    }
#pragma unroll
    for (int j = 0; j < 2; ++j) {
      int c = j * 256 + tid;
      int row = c >> 3, g = (c & 7) ^ (row & 7);
      async16(vbase + (size_t)row * 2048 + kv0 + g * 8, &Vs[buf][c * 16]);
    }
  };

  fvec16 oacc[2] = {};
  fvec16 lacc = {};
  fvec16 sac[2][2];   // double-buffered S^T accumulators (static idx, unrolled)

  auto QK = [&](int sb, int buf) {
    sac[sb][0] = fvec16{};
    sac[sb][1] = fvec16{};
    __builtin_amdgcn_s_setprio(1);
#pragma unroll
    for (int ks = 0; ks < 4; ++ks) {
      const int chunk = ks * 2 + hi;
#pragma unroll
      for (int kvb = 0; kvb < 2; ++kvb) {
        const int r = kvb * 32 + l31;
        bvec8 kf = *(const bvec8*)&Ks[buf][r * 128 + ((chunk ^ (r & 7)) << 4)];
        sac[sb][kvb] = MFMA32(kf, qf[ks], sac[sb][kvb]);
      }
    }
    __builtin_amdgcn_s_setprio(0);
  };

  // prologue: stage 0,1,2; wait stage(0); QK(0)
  stage(0, kvbase);
  stage(1, kvbase + 64);
  stage(2, kvbase + 128);
  asm volatile("s_waitcnt vmcnt(8)" ::: "memory");   // stage(0) complete
  __builtin_amdgcn_sched_barrier(0);
  __builtin_amdgcn_s_barrier();
  QK(0, 0);

#pragma unroll
  for (int t = 0; t < 16; ++t) {
    const int sb = t & 1;
    const int buf = t & 3;

    // ---- counted barrier FIRST (right after PV(t-1)); then prefetch and
    //      QK(t+1) so its MFMA runs under exp2(t)'s VALU chain ----
    if (t < 15) {
      if (t < 14) asm volatile("s_waitcnt vmcnt(4)" ::: "memory");
      else        asm volatile("s_waitcnt vmcnt(0)" ::: "memory");
      __builtin_amdgcn_sched_barrier(0);
      __builtin_amdgcn_s_barrier();
      if (t < 13) stage((t + 3) & 3, kvbase + (t + 3) * 64);
      QK(sb ^ 1, (t + 1) & 3);
    }

    // ---- p = exp2(s) in-register; kv(reg) = 32f+(r&3)+8*(r>>2)+4*hi ----
    ivec4 pw[4];
#pragma unroll
    for (int f = 0; f < 2; ++f) {
      float p[16];
#pragma unroll
      for (int r2 = 0; r2 < 16; ++r2) p[r2] = exp2f(sac[sb][f][r2]);
      int wv[4][2];
#pragma unroll
      for (int m = 0; m < 4; ++m)
#pragma unroll
        for (int i = 0; i < 2; ++i)
          asm("v_cvt_pk_bf16_f32 %0, %1, %2"
              : "=v"(wv[m][i]) : "v"(p[4 * m + 2 * i]), "v"(p[4 * m + 2 * i + 1]));
#pragma unroll
      for (int i = 0; i < 2; ++i) {
        int a0 = wv[0][i], c0 = wv[1][i];
        asm volatile("v_permlane32_swap_b32 %0, %1" : "+v"(a0), "+v"(c0));
        pw[2 * f][i] = a0; pw[2 * f][2 + i] = c0;
        int a1 = wv[2][i], c1 = wv[3][i];
        asm volatile("v_permlane32_swap_b32 %0, %1" : "+v"(a1), "+v"(c1));
        pw[2 * f + 1][i] = a1; pw[2 * f + 1][2 + i] = c1;
      }
    }

    // ---- PV + row-sum: oacc += P @ Vt^T, lacc += P @ ones ----
    __builtin_amdgcn_s_setprio(1);
#pragma unroll
    for (int ks = 0; ks < 4; ++ks) {
      const bvec8 pb = __builtin_bit_cast(bvec8, pw[ks]);
      const int chunk = ks * 2 + hi;
#pragma unroll
      for (int dhb = 0; dhb < 2; ++dhb) {
        const int r = dhb * 32 + l31;
        bvec8 vf = *(const bvec8*)&Vs[buf][r * 128 + ((chunk ^ (r & 7)) << 4)];
        oacc[dhb] = MFMA32(pb, vf, oacc[dhb]);
      }
      lacc = MFMA32(pb, ones, lacc);   // all 32 cols identical = row sum
    }
    __builtin_amdgcn_s_setprio(0);
  }

  // ---- epilogue: unnormalized O + row sums ----
  bf16* pob = po + (size_t)half * 2097152;
#pragma unroll
  for (int dhb = 0; dhb < 2; ++dhb)
#pragma unroll
    for (int r2 = 0; r2 < 16; ++r2) {
      const int q = qw0 + (r2 & 3) + 8 * (r2 >> 2) + 4 * hi;
      pob[(size_t)(b * 2048 + q) * 512 + h * 64 + dhb * 32 + l31] =
          (bf16)oacc[dhb][r2];
    }
  if (l31 == 0) {
#pragma unroll
    for (int r2 = 0; r2 < 16; ++r2) {
      const int q = qw0 + (r2 & 3) + 8 * (r2 >> 2) + 4 * hi;
      pl[half * 32768 + (b * 2048 + q) * 8 + h] = lacc[r2];
    }
  }
}

// ---------------------------------------------------------------------------
// Combine 2 kv-halves: att = (O_0 + O_1) / (l_0 + l_1). 1024 blocks x 256.
// ---------------------------------------------------------------------------
__global__ void combine_kernel(const bf16* __restrict__ po, const float* __restrict__ pl,
                               bf16* __restrict__ att) {
  const int t = blockIdx.x * 256 + threadIdx.x;
  const int row = t >> 6;
  const int c8 = (t & 63) << 3;
  const int h = c8 >> 6;
  const float inv = 1.0f / (pl[row * 8 + h] + pl[32768 + row * 8 + h]);
  bvec8 a0 = *(const bvec8*)(po + (size_t)row * 512 + c8);
  bvec8 a1 = *(const bvec8*)(po + 2097152 + (size_t)row * 512 + c8);
  bvec8 o;
#pragma unroll
  for (int j = 0; j < 8; ++j)
    o[j] = (bf16)(((float)a0[j] + (float)a1[j]) * inv);
  *(bvec8*)(att + (size_t)row * 512 + c8) = o;
}

// ---------------------------------------------------------------------------
// Out GEMM (verified): out = att @ Wc^T + bias (f32 out).
// ---------------------------------------------------------------------------
__launch_bounds__(256, 3)
__global__ void out_gemm(const bf16* __restrict__ X, const bf16* __restrict__ W,
                         const float* __restrict__ bias, float* __restrict__ Y) {
  __shared__ __attribute__((aligned(16))) char As[2][64 * 128];   // 8 KB each
  __shared__ __attribute__((aligned(16))) char Bs[2][128 * 128];  // 16 KB each

  const int tid = threadIdx.x;
  const int w = tid >> 6, l = tid & 63;
  const int wr = w >> 1, wc = w & 1;
  const int l15 = l & 15, lg = l >> 4;
  const int bm0 = blockIdx.x * 64;
  const int bn0 = blockIdx.y * 128;

  fvec4 acc[2][4] = {};

  auto stageA = [&](int buf, int k0) {
#pragma unroll
    for (int j = 0; j < 2; ++j) {
      int c = j * 256 + tid;
      int row = c >> 3, g = (c & 7) ^ (row & 7);
      async16(X + (size_t)(bm0 + row) * 512 + k0 + g * 8, &As[buf][c * 16]);
    }
  };
  auto stageB = [&](int buf, int k0) {
#pragma unroll
    for (int j = 0; j < 4; ++j) {
      int c = j * 256 + tid;
      int row = c >> 3, g = (c & 7) ^ (row & 7);
      async16(W + (size_t)(bn0 + row) * 512 + k0 + g * 8, &Bs[buf][c * 16]);
    }
  };

  stageA(0, 0);
  stageB(0, 0);
  __syncthreads();

  for (int t = 0; t < 8; ++t) {
    const int buf = t & 1;
    if (t < 7) { stageA(buf ^ 1, (t + 1) * 64); stageB(buf ^ 1, (t + 1) * 64); }
#pragma unroll
    for (int kk = 0; kk < 2; ++kk) {
      bvec8 af[2], bfr[4];
      const int g = kk * 4 + lg;
#pragma unroll
      for (int m = 0; m < 2; ++m) {
        int r = wr * 32 + m * 16 + l15;
        af[m] = *(const bvec8*)&As[buf][r * 128 + ((g ^ (r & 7)) << 4)];
      }
#pragma unroll
      for (int n = 0; n < 4; ++n) {
        int r = wc * 64 + n * 16 + l15;
        bfr[n] = *(const bvec8*)&Bs[buf][r * 128 + ((g ^ (r & 7)) << 4)];
      }
#pragma unroll
      for (int m = 0; m < 2; ++m)
#pragma unroll
        for (int n = 0; n < 4; ++n) acc[m][n] = MFMA16(af[m], bfr[n], acc[m][n]);
    }
    __syncthreads();
  }

#pragma unroll
  for (int n = 0; n < 4; ++n) {
    const int col = bn0 + wc * 64 + n * 16 + l15;
    const float bv = bias[col];
#pragma unroll
    for (int m = 0; m < 2; ++m) {
      const int row0 = bm0 + wr * 32 + m * 16 + lg * 4;
#pragma unroll
      for (int r = 0; r < 4; ++r)
        Y[(size_t)(row0 + r) * 512 + col] = acc[m][n][r] + bv;
    }
  }
}

// ---------------------------------------------------------------------------
extern "C" void kernel_launch(void* const* d_in, const int* in_sizes, int n_in,
                              void* d_out, int out_size, void* d_ws, size_t ws_size,
                              hipStream_t stream) {
  const float* q   = (const float*)d_in[0];
  const float* k   = (const float*)d_in[1];
  const float* v   = (const float*)d_in[2];
  const float* Wq  = (const float*)d_in[3];
  const float* Wqb = (const float*)d_in[4];
  const float* Wc  = (const float*)d_in[5];
  const float* Wcb = (const float*)d_in[6];
  float* out = (float*)d_out;

  char* ws = (char*)d_ws;
  const size_t MB = 1u << 20;
  bf16* qkvb = (bf16*)(ws);                        // [3][4096][512], 0..12MB
  bf16* po   = (bf16*)(ws);                        // [2][4096][512] reuses qkvb
  bf16* att  = (bf16*)(ws + 8 * MB);               // [4096][512], 8..12MB
  bf16* Wq16 = (bf16*)(ws + 12 * MB);              // 0.5MB
  bf16* Wc16 = (bf16*)(ws + 12 * MB + 512 * 1024); // 0.5MB
  bf16* qkp  = (bf16*)(ws + 13 * MB);              // [8192][512], 13..21MB
  bf16* vt   = (bf16*)(ws + 21 * MB);              // [b][h][dh][2048], 21..25MB
  float* pl  = (float*)(ws + 33 * MB);             // [2][4096][8] f32, 256KB

  dim3 bb(256);
  hipLaunchKernelGGL(cvt_all, dim3(3328), bb, 0, stream, q, k, v, Wq, Wc,
                     qkvb, Wq16, Wc16);
  hipLaunchKernelGGL(proj_gemm, dim3(192, 4), bb, 0, stream,
                     qkvb, Wq16, Wqb, qkp, vt);
  hipLaunchKernelGGL(attn_kernel, dim3(16, 16, 2), bb, 0, stream,
                     qkp, qkp + 2097152, vt, po, pl);
  hipLaunchKernelGGL(combine_kernel, dim3(1024), bb, 0, stream, po, pl, att);
  hipLaunchKernelGGL(out_gemm, dim3(64, 4), bb, 0, stream,
                     att, Wc16, Wcb, out);
}

// Round 15
// 68.374 us; speedup vs baseline: 1.0008x; 1.0008x over previous
//
#include <hip/hip_runtime.h>
#include <hip/hip_bf16.h>
#include <stdint.h>

// MultiHead attention: B=2, S=2048, D=512, H=8, dh=64. f32 I/O, bf16 MFMA core.
// NOTE: reference projects q,k,v ALL with Wq (faithful to original bug).
// v15 = v14 with the normalization bug FIXED: l is per (row, HEAD) and the
//   out-GEMM K-sum spans 8 heads, so division must happen per-chunk in the
//   A-staging (each 8-elem chunk is within one head), not in the epilogue.
//   writeA scales by 1/(l0+l1) of the chunk's head before the bf16 round --
//   bit-comparable to the retired combine kernel. 4 dispatches.

typedef __bf16 bf16;
typedef __bf16 bvec8 __attribute__((ext_vector_type(8)));
typedef __bf16 bvec4 __attribute__((ext_vector_type(4)));
typedef float  fvec4 __attribute__((ext_vector_type(4)));
typedef float  fvec16 __attribute__((ext_vector_type(16)));
typedef int    ivec4 __attribute__((ext_vector_type(4)));

#define MFMA16(a, b, c) __builtin_amdgcn_mfma_f32_16x16x32_bf16(a, b, c, 0, 0, 0)
#define MFMA32(a, b, c) __builtin_amdgcn_mfma_f32_32x32x16_bf16(a, b, c, 0, 0, 0)

// async global->LDS, 16B per lane. HW: wave-uniform LDS base + lane*16.
__device__ __forceinline__ void async16(const void* g, void* l) {
  __builtin_amdgcn_global_load_lds(
      (__attribute__((address_space(1))) void*)(g),
      (__attribute__((address_space(3))) void*)(l), 16, 0, 0);
}

// ---------------------------------------------------------------------------
// All f32->bf16 conversions in ONE launch: q,k,v -> qkvb[3][4096][512],
// Wq -> Wq16, Wc -> Wc16. 8 elems/thread.
// ---------------------------------------------------------------------------
__global__ void cvt_all(const float* __restrict__ q, const float* __restrict__ k,
                        const float* __restrict__ v, const float* __restrict__ Wq,
                        const float* __restrict__ Wc, bf16* __restrict__ qkvb,
                        bf16* __restrict__ Wq16, bf16* __restrict__ Wc16) {
  const int t = blockIdx.x * 256 + threadIdx.x;
  const float* src;
  bf16* dst;
  size_t i;
  if (t < 786432) {                       // 3 * 2^18 threads for q,k,v
    const int which = t >> 18;
    i = (size_t)(t & 262143);
    src = (which == 0) ? q : (which == 1) ? k : v;
    dst = qkvb + ((size_t)which << 21);   // 2^21 elems per tensor
  } else if (t < 819200) {
    src = Wq; dst = Wq16; i = (size_t)(t - 786432);
  } else {
    src = Wc; dst = Wc16; i = (size_t)(t - 819200);
  }
  fvec4 a = *(const fvec4*)(src + i * 8);
  fvec4 b = *(const fvec4*)(src + i * 8 + 4);
  bvec8 o;
#pragma unroll
  for (int j = 0; j < 4; ++j) { o[j] = (bf16)a[j]; o[j + 4] = (bf16)b[j]; }
  *(bvec8*)(dst + i * 8) = o;
}

// ---------------------------------------------------------------------------
// Projection GEMM: Y[12288,512] = X @ Wq^T + bias (bf16 in, fp32 acc).
// BM=64, BN=128, BK=64; 256 threads (2x2 waves, wave tile 32x64).
// LDS XOR swizzle (16B chunk g of row r at pos g^(r&7); inverse on DMA src).
// Rows < 4096 (q third): result scaled by SC=log2(e)/8 before bf16 round.
// Rows >= 8192 (v third): store transposed per-head into Yt.
// ---------------------------------------------------------------------------
__launch_bounds__(256, 3)
__global__ void proj_gemm(const bf16* __restrict__ X, const bf16* __restrict__ W,
                          const float* __restrict__ bias, bf16* __restrict__ Y,
                          bf16* __restrict__ Yt) {
  __shared__ __attribute__((aligned(16))) char As[2][64 * 128];   // 8 KB each
  __shared__ __attribute__((aligned(16))) char Bs[2][128 * 128];  // 16 KB each

  const int tid = threadIdx.x;
  const int w = tid >> 6, l = tid & 63;
  const int wr = w >> 1, wc = w & 1;
  const int l15 = l & 15, lg = l >> 4;
  const int bm0 = blockIdx.x * 64;
  const int bn0 = blockIdx.y * 128;

  fvec4 acc[2][4] = {};

  auto stageA = [&](int buf, int k0) {
#pragma unroll
    for (int j = 0; j < 2; ++j) {
      int c = j * 256 + tid;
      int row = c >> 3, g = (c & 7) ^ (row & 7);
      async16(X + (size_t)(bm0 + row) * 512 + k0 + g * 8, &As[buf][c * 16]);
    }
  };
  auto stageB = [&](int buf, int k0) {
#pragma unroll
    for (int j = 0; j < 4; ++j) {
      int c = j * 256 + tid;
      int row = c >> 3, g = (c & 7) ^ (row & 7);
      async16(W + (size_t)(bn0 + row) * 512 + k0 + g * 8, &Bs[buf][c * 16]);
    }
  };

  stageA(0, 0);
  stageB(0, 0);
  __syncthreads();

  for (int t = 0; t < 8; ++t) {
    const int buf = t & 1;
    if (t < 7) { stageA(buf ^ 1, (t + 1) * 64); stageB(buf ^ 1, (t + 1) * 64); }
#pragma unroll
    for (int kk = 0; kk < 2; ++kk) {
      bvec8 af[2], bfr[4];
      const int g = kk * 4 + lg;
#pragma unroll
      for (int m = 0; m < 2; ++m) {
        int r = wr * 32 + m * 16 + l15;
        af[m] = *(const bvec8*)&As[buf][r * 128 + ((g ^ (r & 7)) << 4)];
      }
#pragma unroll
      for (int n = 0; n < 4; ++n) {
        int r = wc * 64 + n * 16 + l15;
        bfr[n] = *(const bvec8*)&Bs[buf][r * 128 + ((g ^ (r & 7)) << 4)];
      }
#pragma unroll
      for (int m = 0; m < 2; ++m)
#pragma unroll
        for (int n = 0; n < 4; ++n) acc[m][n] = MFMA16(af[m], bfr[n], acc[m][n]);
    }
    __syncthreads();
  }

  // Epilogue. C layout: col = lane&15, rows = (lane>>4)*4 + r.
  const bool trans = (bm0 >= 8192);
  const float scl = (bm0 < 4096) ? 0.18033688011112042f : 1.0f;  // log2(e)/8
#pragma unroll
  for (int n = 0; n < 4; ++n) {
    const int col = bn0 + wc * 64 + n * 16 + l15;
    const float bv = bias[col];
#pragma unroll
    for (int m = 0; m < 2; ++m) {
      const int row0 = bm0 + wr * 32 + m * 16 + lg * 4;
      if (!trans) {
#pragma unroll
        for (int r = 0; r < 4; ++r)
          Y[(size_t)(row0 + r) * 512 + col] = (bf16)((acc[m][n][r] + bv) * scl);
      } else {
        const int m0 = row0 - 8192;
        const int b = m0 >> 11, s = m0 & 2047;
        bvec4 v4;
#pragma unroll
        for (int r = 0; r < 4; ++r) v4[r] = (bf16)(acc[m][n][r] + bv);
        *(bvec4*)&Yt[(size_t)(b * 512 + col) * 2048 + s] = v4;
      }
    }
  }
}

// ---------------------------------------------------------------------------
// Flash attention (v12 exact). Grid (16 qb, 16 bh, 2 kv-halves) = 512 blocks,
// 2 blocks/CU. 16 tiles/block, cross-tile pipeline:
//   iter t: exp2/pack(t) | vmcnt(4)+barrier | stage(t+3) | QK(t+1) | PV(t)
// 4 LDS buffers (64 KB). Swapped QK^T (Q pre-scaled log2(e)/8) -> p=exp2(s)
// lane-local; P via v_cvt_pk_bf16_f32 + permlane32_swap; PV + ones-MFMA
// row sums.
// ---------------------------------------------------------------------------
__launch_bounds__(256, 2)
__global__ void attn_kernel(const bf16* __restrict__ qp, const bf16* __restrict__ kp,
                            const bf16* __restrict__ vt, bf16* __restrict__ po,
                            float* __restrict__ pl) {
  __shared__ __attribute__((aligned(16))) char Ks[4][64 * 128];  // 8 KB each
  __shared__ __attribute__((aligned(16))) char Vs[4][64 * 128];

  const int tid = threadIdx.x;
  const int w = tid >> 6, l = tid & 63;
  const int l31 = l & 31, hi = l >> 5;
  const int bh = blockIdx.y, b = bh >> 3, h = bh & 7;
  const int half = blockIdx.z;
  const int kvbase = half * 1024;
  const int qw0 = blockIdx.x * 128 + w * 32;

  const bf16* kbase = kp + (size_t)(b * 2048) * 512 + h * 64;
  const bf16* vbase = vt + (size_t)(b * 512 + h * 64) * 2048;

  bvec8 qf[4];
  {
    const bf16* qrow = qp + (size_t)(b * 2048 + qw0 + l31) * 512 + h * 64 + hi * 8;
#pragma unroll
    for (int ks = 0; ks < 4; ++ks) qf[ks] = *(const bvec8*)(qrow + ks * 16);
  }
  bvec8 ones;
#pragma unroll
  for (int e = 0; e < 8; ++e) ones[e] = (bf16)1.0f;

  // one stage = 2 K-loads + 2 V-loads per thread (vmcnt 4/stage/wave)
  auto stage = [&](int buf, int kv0) {
#pragma unroll
    for (int j = 0; j < 2; ++j) {
      int c = j * 256 + tid;
      int row = c >> 3, g = (c & 7) ^ (row & 7);
      async16(kbase + (size_t)(kv0 + row) * 512 + g * 8, &Ks[buf][c * 16]);
    }
#pragma unroll
    for (int j = 0; j < 2; ++j) {
      int c = j * 256 + tid;
      int row = c >> 3, g = (c & 7) ^ (row & 7);
      async16(vbase + (size_t)row * 2048 + kv0 + g * 8, &Vs[buf][c * 16]);
    }
  };

  fvec16 oacc[2] = {};
  fvec16 lacc = {};
  fvec16 sac[2][2];   // double-buffered S^T accumulators (static idx, unrolled)

  auto QK = [&](int sb, int buf) {
    sac[sb][0] = fvec16{};
    sac[sb][1] = fvec16{};
    __builtin_amdgcn_s_setprio(1);
#pragma unroll
    for (int ks = 0; ks < 4; ++ks) {
      const int chunk = ks * 2 + hi;
#pragma unroll
      for (int kvb = 0; kvb < 2; ++kvb) {
        const int r = kvb * 32 + l31;
        bvec8 kf = *(const bvec8*)&Ks[buf][r * 128 + ((chunk ^ (r & 7)) << 4)];
        sac[sb][kvb] = MFMA32(kf, qf[ks], sac[sb][kvb]);
      }
    }
    __builtin_amdgcn_s_setprio(0);
  };

  // prologue: stage 0,1,2; wait stage(0); QK(0)
  stage(0, kvbase);
  stage(1, kvbase + 64);
  stage(2, kvbase + 128);
  asm volatile("s_waitcnt vmcnt(8)" ::: "memory");   // stage(0) complete
  __builtin_amdgcn_sched_barrier(0);
  __builtin_amdgcn_s_barrier();
  QK(0, 0);

#pragma unroll
  for (int t = 0; t < 16; ++t) {
    const int sb = t & 1;
    const int buf = t & 3;

    // ---- p = exp2(s) in-register; kv(reg) = 32f+(r&3)+8*(r>>2)+4*hi ----
    ivec4 pw[4];
#pragma unroll
    for (int f = 0; f < 2; ++f) {
      float p[16];
#pragma unroll
      for (int r2 = 0; r2 < 16; ++r2) p[r2] = exp2f(sac[sb][f][r2]);
      int wv[4][2];
#pragma unroll
      for (int m = 0; m < 4; ++m)
#pragma unroll
        for (int i = 0; i < 2; ++i)
          asm("v_cvt_pk_bf16_f32 %0, %1, %2"
              : "=v"(wv[m][i]) : "v"(p[4 * m + 2 * i]), "v"(p[4 * m + 2 * i + 1]));
#pragma unroll
      for (int i = 0; i < 2; ++i) {
        int a0 = wv[0][i], c0 = wv[1][i];
        asm volatile("v_permlane32_swap_b32 %0, %1" : "+v"(a0), "+v"(c0));
        pw[2 * f][i] = a0; pw[2 * f][2 + i] = c0;
        int a1 = wv[2][i], c1 = wv[3][i];
        asm volatile("v_permlane32_swap_b32 %0, %1" : "+v"(a1), "+v"(c1));
        pw[2 * f + 1][i] = a1; pw[2 * f + 1][2 + i] = c1;
      }
    }

    // ---- counted barrier; prefetch t+3; QK(t+1) bridges exp2->PV chain ----
    if (t < 15) {
      if (t < 14) asm volatile("s_waitcnt vmcnt(4)" ::: "memory");
      else        asm volatile("s_waitcnt vmcnt(0)" ::: "memory");
      __builtin_amdgcn_sched_barrier(0);
      __builtin_amdgcn_s_barrier();
      if (t < 13) stage((t + 3) & 3, kvbase + (t + 3) * 64);
      QK(sb ^ 1, (t + 1) & 3);
    }

    // ---- PV + row-sum: oacc += P @ Vt^T, lacc += P @ ones ----
    __builtin_amdgcn_s_setprio(1);
#pragma unroll
    for (int ks = 0; ks < 4; ++ks) {
      const bvec8 pb = __builtin_bit_cast(bvec8, pw[ks]);
      const int chunk = ks * 2 + hi;
#pragma unroll
      for (int dhb = 0; dhb < 2; ++dhb) {
        const int r = dhb * 32 + l31;
        bvec8 vf = *(const bvec8*)&Vs[buf][r * 128 + ((chunk ^ (r & 7)) << 4)];
        oacc[dhb] = MFMA32(pb, vf, oacc[dhb]);
      }
      lacc = MFMA32(pb, ones, lacc);   // all 32 cols identical = row sum
    }
    __builtin_amdgcn_s_setprio(0);
  }

  // ---- epilogue: unnormalized O + row sums ----
  bf16* pob = po + (size_t)half * 2097152;
#pragma unroll
  for (int dhb = 0; dhb < 2; ++dhb)
#pragma unroll
    for (int r2 = 0; r2 < 16; ++r2) {
      const int q = qw0 + (r2 & 3) + 8 * (r2 >> 2) + 4 * hi;
      pob[(size_t)(b * 2048 + q) * 512 + h * 64 + dhb * 32 + l31] =
          (bf16)oacc[dhb][r2];
    }
  if (l31 == 0) {
#pragma unroll
    for (int r2 = 0; r2 < 16; ++r2) {
      const int q = qw0 + (r2 & 3) + 8 * (r2 >> 2) + 4 * hi;
      pl[half * 32768 + (b * 2048 + q) * 8 + h] = lacc[r2];
    }
  }
}

// ---------------------------------------------------------------------------
// Out GEMM with fused combine (FIXED): A-staging normalizes per chunk --
// each 8-elem chunk lies within ONE head (k = k0+g*8 .. +8), so
// att_chunk = (po0+po1) * 1/(l0+l1) of that (row, head). Bit-comparable to
// the retired combine kernel. B = Wc16 via DMA. Plain epilogue.
// ---------------------------------------------------------------------------
__launch_bounds__(256, 3)
__global__ void out_gemm(const bf16* __restrict__ po, const float* __restrict__ pl,
                         const bf16* __restrict__ W, const float* __restrict__ bias,
                         float* __restrict__ Y) {
  __shared__ __attribute__((aligned(16))) char As[2][64 * 128];   // 8 KB each
  __shared__ __attribute__((aligned(16))) char Bs[2][128 * 128];  // 16 KB each

  const int tid = threadIdx.x;
  const int w = tid >> 6, l = tid & 63;
  const int wr = w >> 1, wc = w & 1;
  const int l15 = l & 15, lg = l >> 4;
  const int bm0 = blockIdx.x * 64;
  const int bn0 = blockIdx.y * 128;

  fvec4 acc[2][4] = {};
  bvec8 rp[2][2];   // staged partial pairs per chunk
  float rl[2][2];   // staged pl pair (chunk's row, head)

  auto loadA = [&](int k0) {
#pragma unroll
    for (int j = 0; j < 2; ++j) {
      int c = j * 256 + tid;
      int row = c >> 3, g = (c & 7) ^ (row & 7);
      const size_t off = (size_t)(bm0 + row) * 512 + k0 + g * 8;
      rp[j][0] = *(const bvec8*)(po + off);
      rp[j][1] = *(const bvec8*)(po + 2097152 + off);
      const int ridx = (bm0 + row) * 8 + ((k0 + g * 8) >> 6);
      rl[j][0] = pl[ridx];
      rl[j][1] = pl[32768 + ridx];
    }
  };
  auto writeA = [&](int buf) {
#pragma unroll
    for (int j = 0; j < 2; ++j) {
      int c = j * 256 + tid;
      const float inv = 1.0f / (rl[j][0] + rl[j][1]);
      bvec8 o;
#pragma unroll
      for (int e = 0; e < 8; ++e)
        o[e] = (bf16)(((float)rp[j][0][e] + (float)rp[j][1][e]) * inv);
      *(bvec8*)&As[buf][c * 16] = o;
    }
  };
  auto stageB = [&](int buf, int k0) {
#pragma unroll
    for (int j = 0; j < 4; ++j) {
      int c = j * 256 + tid;
      int row = c >> 3, g = (c & 7) ^ (row & 7);
      async16(W + (size_t)(bn0 + row) * 512 + k0 + g * 8, &Bs[buf][c * 16]);
    }
  };

  loadA(0);
  stageB(0, 0);
  writeA(0);
  __syncthreads();

  for (int t = 0; t < 8; ++t) {
    const int buf = t & 1;
    if (t < 7) {                       // issue next-tile loads EARLY
      loadA((t + 1) * 64);
      stageB(buf ^ 1, (t + 1) * 64);
    }
#pragma unroll
    for (int kk = 0; kk < 2; ++kk) {
      bvec8 af[2], bfr[4];
      const int g = kk * 4 + lg;
#pragma unroll
      for (int m = 0; m < 2; ++m) {
        int r = wr * 32 + m * 16 + l15;
        af[m] = *(const bvec8*)&As[buf][r * 128 + ((g ^ (r & 7)) << 4)];
      }
#pragma unroll
      for (int n = 0; n < 4; ++n) {
        int r = wc * 64 + n * 16 + l15;
        bfr[n] = *(const bvec8*)&Bs[buf][r * 128 + ((g ^ (r & 7)) << 4)];
      }
#pragma unroll
      for (int m = 0; m < 2; ++m)
#pragma unroll
        for (int n = 0; n < 4; ++n) acc[m][n] = MFMA16(af[m], bfr[n], acc[m][n]);
    }
    if (t < 7) writeA(buf ^ 1);        // normalize+cvt+ds_write LATE
    __syncthreads();
  }

  // Epilogue: plain bias add (normalization already in staging).
#pragma unroll
  for (int n = 0; n < 4; ++n) {
    const int col = bn0 + wc * 64 + n * 16 + l15;
    const float bv = bias[col];
#pragma unroll
    for (int m = 0; m < 2; ++m) {
      const int row0 = bm0 + wr * 32 + m * 16 + lg * 4;
#pragma unroll
      for (int r = 0; r < 4; ++r)
        Y[(size_t)(row0 + r) * 512 + col] = acc[m][n][r] + bv;
    }
  }
}

// ---------------------------------------------------------------------------
extern "C" void kernel_launch(void* const* d_in, const int* in_sizes, int n_in,
                              void* d_out, int out_size, void* d_ws, size_t ws_size,
                              hipStream_t stream) {
  const float* q   = (const float*)d_in[0];
  const float* k   = (const float*)d_in[1];
  const float* v   = (const float*)d_in[2];
  const float* Wq  = (const float*)d_in[3];
  const float* Wqb = (const float*)d_in[4];
  const float* Wc  = (const float*)d_in[5];
  const float* Wcb = (const float*)d_in[6];
  float* out = (float*)d_out;

  char* ws = (char*)d_ws;
  const size_t MB = 1u << 20;
  bf16* qkvb = (bf16*)(ws);                        // [3][4096][512], 0..12MB
  bf16* po   = (bf16*)(ws);                        // [2][4096][512] reuses qkvb
  bf16* Wq16 = (bf16*)(ws + 12 * MB);              // 0.5MB
  bf16* Wc16 = (bf16*)(ws + 12 * MB + 512 * 1024); // 0.5MB
  bf16* qkp  = (bf16*)(ws + 13 * MB);              // [8192][512], 13..21MB
  bf16* vt   = (bf16*)(ws + 21 * MB);              // [b][h][dh][2048], 21..25MB
  float* pl  = (float*)(ws + 33 * MB);             // [2][4096][8] f32, 256KB

  dim3 bb(256);
  hipLaunchKernelGGL(cvt_all, dim3(3328), bb, 0, stream, q, k, v, Wq, Wc,
                     qkvb, Wq16, Wc16);
  hipLaunchKernelGGL(proj_gemm, dim3(192, 4), bb, 0, stream,
                     qkvb, Wq16, Wqb, qkp, vt);
  hipLaunchKernelGGL(attn_kernel, dim3(16, 16, 2), bb, 0, stream,
                     qkp, qkp + 2097152, vt, po, pl);
  hipLaunchKernelGGL(out_gemm, dim3(64, 4), bb, 0, stream,
                     po, pl, Wc16, Wcb, out);
}

// Round 16
// 67.260 us; speedup vs baseline: 1.0174x; 1.0166x over previous
//
#include <hip/hip_runtime.h>
#include <hip/hip_bf16.h>
#include <stdint.h>

// MultiHead attention: B=2, S=2048, D=512, H=8, dh=64. f32 I/O, bf16 MFMA core.
// NOTE: reference projects q,k,v ALL with Wq (faithful to original bug).
// FINAL (= v12, measured best 67.38us): 5 dispatches.
//   cvt_all -> proj_gemm (Q pre-scaled log2(e)/8; V stored transposed)
//   -> attn (split-2, cross-tile pipeline: exp2(t) | counted-vmcnt barrier |
//      stage(t+3) | QK(t+1) | PV(t); 4 LDS buffers, swapped QK^T, in-register
//      softmax, cvt_pk+permlane32 P-pack, ones-MFMA row sums)
//   -> combine -> out_gemm.

typedef __bf16 bf16;
typedef __bf16 bvec8 __attribute__((ext_vector_type(8)));
typedef __bf16 bvec4 __attribute__((ext_vector_type(4)));
typedef float  fvec4 __attribute__((ext_vector_type(4)));
typedef float  fvec16 __attribute__((ext_vector_type(16)));
typedef int    ivec4 __attribute__((ext_vector_type(4)));

#define MFMA16(a, b, c) __builtin_amdgcn_mfma_f32_16x16x32_bf16(a, b, c, 0, 0, 0)
#define MFMA32(a, b, c) __builtin_amdgcn_mfma_f32_32x32x16_bf16(a, b, c, 0, 0, 0)

// async global->LDS, 16B per lane. HW: wave-uniform LDS base + lane*16.
__device__ __forceinline__ void async16(const void* g, void* l) {
  __builtin_amdgcn_global_load_lds(
      (__attribute__((address_space(1))) void*)(g),
      (__attribute__((address_space(3))) void*)(l), 16, 0, 0);
}

// ---------------------------------------------------------------------------
// All f32->bf16 conversions in ONE launch: q,k,v -> qkvb[3][4096][512],
// Wq -> Wq16, Wc -> Wc16. 8 elems/thread.
// ---------------------------------------------------------------------------
__global__ void cvt_all(const float* __restrict__ q, const float* __restrict__ k,
                        const float* __restrict__ v, const float* __restrict__ Wq,
                        const float* __restrict__ Wc, bf16* __restrict__ qkvb,
                        bf16* __restrict__ Wq16, bf16* __restrict__ Wc16) {
  const int t = blockIdx.x * 256 + threadIdx.x;
  const float* src;
  bf16* dst;
  size_t i;
  if (t < 786432) {                       // 3 * 2^18 threads for q,k,v
    const int which = t >> 18;
    i = (size_t)(t & 262143);
    src = (which == 0) ? q : (which == 1) ? k : v;
    dst = qkvb + ((size_t)which << 21);   // 2^21 elems per tensor
  } else if (t < 819200) {
    src = Wq; dst = Wq16; i = (size_t)(t - 786432);
  } else {
    src = Wc; dst = Wc16; i = (size_t)(t - 819200);
  }
  fvec4 a = *(const fvec4*)(src + i * 8);
  fvec4 b = *(const fvec4*)(src + i * 8 + 4);
  bvec8 o;
#pragma unroll
  for (int j = 0; j < 4; ++j) { o[j] = (bf16)a[j]; o[j + 4] = (bf16)b[j]; }
  *(bvec8*)(dst + i * 8) = o;
}

// ---------------------------------------------------------------------------
// Projection GEMM: Y[12288,512] = X @ Wq^T + bias (bf16 in, fp32 acc).
// BM=64, BN=128, BK=64; 256 threads (2x2 waves, wave tile 32x64).
// LDS XOR swizzle (16B chunk g of row r at pos g^(r&7); inverse on DMA src).
// Rows < 4096 (q third): result scaled by SC=log2(e)/8 before bf16 round.
// Rows >= 8192 (v third): store transposed per-head into Yt.
// ---------------------------------------------------------------------------
__launch_bounds__(256, 3)
__global__ void proj_gemm(const bf16* __restrict__ X, const bf16* __restrict__ W,
                          const float* __restrict__ bias, bf16* __restrict__ Y,
                          bf16* __restrict__ Yt) {
  __shared__ __attribute__((aligned(16))) char As[2][64 * 128];   // 8 KB each
  __shared__ __attribute__((aligned(16))) char Bs[2][128 * 128];  // 16 KB each

  const int tid = threadIdx.x;
  const int w = tid >> 6, l = tid & 63;
  const int wr = w >> 1, wc = w & 1;
  const int l15 = l & 15, lg = l >> 4;
  const int bm0 = blockIdx.x * 64;
  const int bn0 = blockIdx.y * 128;

  fvec4 acc[2][4] = {};

  auto stageA = [&](int buf, int k0) {
#pragma unroll
    for (int j = 0; j < 2; ++j) {
      int c = j * 256 + tid;
      int row = c >> 3, g = (c & 7) ^ (row & 7);
      async16(X + (size_t)(bm0 + row) * 512 + k0 + g * 8, &As[buf][c * 16]);
    }
  };
  auto stageB = [&](int buf, int k0) {
#pragma unroll
    for (int j = 0; j < 4; ++j) {
      int c = j * 256 + tid;
      int row = c >> 3, g = (c & 7) ^ (row & 7);
      async16(W + (size_t)(bn0 + row) * 512 + k0 + g * 8, &Bs[buf][c * 16]);
    }
  };

  stageA(0, 0);
  stageB(0, 0);
  __syncthreads();

  for (int t = 0; t < 8; ++t) {
    const int buf = t & 1;
    if (t < 7) { stageA(buf ^ 1, (t + 1) * 64); stageB(buf ^ 1, (t + 1) * 64); }
#pragma unroll
    for (int kk = 0; kk < 2; ++kk) {
      bvec8 af[2], bfr[4];
      const int g = kk * 4 + lg;
#pragma unroll
      for (int m = 0; m < 2; ++m) {
        int r = wr * 32 + m * 16 + l15;
        af[m] = *(const bvec8*)&As[buf][r * 128 + ((g ^ (r & 7)) << 4)];
      }
#pragma unroll
      for (int n = 0; n < 4; ++n) {
        int r = wc * 64 + n * 16 + l15;
        bfr[n] = *(const bvec8*)&Bs[buf][r * 128 + ((g ^ (r & 7)) << 4)];
      }
#pragma unroll
      for (int m = 0; m < 2; ++m)
#pragma unroll
        for (int n = 0; n < 4; ++n) acc[m][n] = MFMA16(af[m], bfr[n], acc[m][n]);
    }
    __syncthreads();
  }

  // Epilogue. C layout: col = lane&15, rows = (lane>>4)*4 + r.
  const bool trans = (bm0 >= 8192);
  const float scl = (bm0 < 4096) ? 0.18033688011112042f : 1.0f;  // log2(e)/8
#pragma unroll
  for (int n = 0; n < 4; ++n) {
    const int col = bn0 + wc * 64 + n * 16 + l15;
    const float bv = bias[col];
#pragma unroll
    for (int m = 0; m < 2; ++m) {
      const int row0 = bm0 + wr * 32 + m * 16 + lg * 4;
      if (!trans) {
#pragma unroll
        for (int r = 0; r < 4; ++r)
          Y[(size_t)(row0 + r) * 512 + col] = (bf16)((acc[m][n][r] + bv) * scl);
      } else {
        const int m0 = row0 - 8192;
        const int b = m0 >> 11, s = m0 & 2047;
        bvec4 v4;
#pragma unroll
        for (int r = 0; r < 4; ++r) v4[r] = (bf16)(acc[m][n][r] + bv);
        *(bvec4*)&Yt[(size_t)(b * 512 + col) * 2048 + s] = v4;
      }
    }
  }
}

// ---------------------------------------------------------------------------
// Flash attention (v12). Grid (16 qb, 16 bh, 2 kv-halves) = 512 blocks,
// 2 blocks/CU. 16 tiles/block, cross-tile pipeline:
//   iter t: exp2/pack(t) | vmcnt(4)+barrier | stage(t+3) | QK(t+1) | PV(t)
// 4 LDS buffers (64 KB). Swapped QK^T (Q pre-scaled log2(e)/8) -> p=exp2(s)
// lane-local; P via v_cvt_pk_bf16_f32 + permlane32_swap; PV + ones-MFMA
// row sums.
// ---------------------------------------------------------------------------
__launch_bounds__(256, 2)
__global__ void attn_kernel(const bf16* __restrict__ qp, const bf16* __restrict__ kp,
                            const bf16* __restrict__ vt, bf16* __restrict__ po,
                            float* __restrict__ pl) {
  __shared__ __attribute__((aligned(16))) char Ks[4][64 * 128];  // 8 KB each
  __shared__ __attribute__((aligned(16))) char Vs[4][64 * 128];

  const int tid = threadIdx.x;
  const int w = tid >> 6, l = tid & 63;
  const int l31 = l & 31, hi = l >> 5;
  const int bh = blockIdx.y, b = bh >> 3, h = bh & 7;
  const int half = blockIdx.z;
  const int kvbase = half * 1024;
  const int qw0 = blockIdx.x * 128 + w * 32;

  const bf16* kbase = kp + (size_t)(b * 2048) * 512 + h * 64;
  const bf16* vbase = vt + (size_t)(b * 512 + h * 64) * 2048;

  bvec8 qf[4];
  {
    const bf16* qrow = qp + (size_t)(b * 2048 + qw0 + l31) * 512 + h * 64 + hi * 8;
#pragma unroll
    for (int ks = 0; ks < 4; ++ks) qf[ks] = *(const bvec8*)(qrow + ks * 16);
  }
  bvec8 ones;
#pragma unroll
  for (int e = 0; e < 8; ++e) ones[e] = (bf16)1.0f;

  // one stage = 2 K-loads + 2 V-loads per thread (vmcnt 4/stage/wave)
  auto stage = [&](int buf, int kv0) {
#pragma unroll
    for (int j = 0; j < 2; ++j) {
      int c = j * 256 + tid;
      int row = c >> 3, g = (c & 7) ^ (row & 7);
      async16(kbase + (size_t)(kv0 + row) * 512 + g * 8, &Ks[buf][c * 16]);
    }
#pragma unroll
    for (int j = 0; j < 2; ++j) {
      int c = j * 256 + tid;
      int row = c >> 3, g = (c & 7) ^ (row & 7);
      async16(vbase + (size_t)row * 2048 + kv0 + g * 8, &Vs[buf][c * 16]);
    }
  };

  fvec16 oacc[2] = {};
  fvec16 lacc = {};
  fvec16 sac[2][2];   // double-buffered S^T accumulators (static idx, unrolled)

  auto QK = [&](int sb, int buf) {
    sac[sb][0] = fvec16{};
    sac[sb][1] = fvec16{};
    __builtin_amdgcn_s_setprio(1);
#pragma unroll
    for (int ks = 0; ks < 4; ++ks) {
      const int chunk = ks * 2 + hi;
#pragma unroll
      for (int kvb = 0; kvb < 2; ++kvb) {
        const int r = kvb * 32 + l31;
        bvec8 kf = *(const bvec8*)&Ks[buf][r * 128 + ((chunk ^ (r & 7)) << 4)];
        sac[sb][kvb] = MFMA32(kf, qf[ks], sac[sb][kvb]);
      }
    }
    __builtin_amdgcn_s_setprio(0);
  };

  // prologue: stage 0,1,2; wait stage(0); QK(0)
  stage(0, kvbase);
  stage(1, kvbase + 64);
  stage(2, kvbase + 128);
  asm volatile("s_waitcnt vmcnt(8)" ::: "memory");   // stage(0) complete
  __builtin_amdgcn_sched_barrier(0);
  __builtin_amdgcn_s_barrier();
  QK(0, 0);

#pragma unroll
  for (int t = 0; t < 16; ++t) {
    const int sb = t & 1;
    const int buf = t & 3;

    // ---- p = exp2(s) in-register; kv(reg) = 32f+(r&3)+8*(r>>2)+4*hi ----
    ivec4 pw[4];
#pragma unroll
    for (int f = 0; f < 2; ++f) {
      float p[16];
#pragma unroll
      for (int r2 = 0; r2 < 16; ++r2) p[r2] = exp2f(sac[sb][f][r2]);
      int wv[4][2];
#pragma unroll
      for (int m = 0; m < 4; ++m)
#pragma unroll
        for (int i = 0; i < 2; ++i)
          asm("v_cvt_pk_bf16_f32 %0, %1, %2"
              : "=v"(wv[m][i]) : "v"(p[4 * m + 2 * i]), "v"(p[4 * m + 2 * i + 1]));
#pragma unroll
      for (int i = 0; i < 2; ++i) {
        int a0 = wv[0][i], c0 = wv[1][i];
        asm volatile("v_permlane32_swap_b32 %0, %1" : "+v"(a0), "+v"(c0));
        pw[2 * f][i] = a0; pw[2 * f][2 + i] = c0;
        int a1 = wv[2][i], c1 = wv[3][i];
        asm volatile("v_permlane32_swap_b32 %0, %1" : "+v"(a1), "+v"(c1));
        pw[2 * f + 1][i] = a1; pw[2 * f + 1][2 + i] = c1;
      }
    }

    // ---- counted barrier; prefetch t+3; QK(t+1) bridges exp2->PV chain ----
    if (t < 15) {
      if (t < 14) asm volatile("s_waitcnt vmcnt(4)" ::: "memory");
      else        asm volatile("s_waitcnt vmcnt(0)" ::: "memory");
      __builtin_amdgcn_sched_barrier(0);
      __builtin_amdgcn_s_barrier();
      if (t < 13) stage((t + 3) & 3, kvbase + (t + 3) * 64);
      QK(sb ^ 1, (t + 1) & 3);
    }

    // ---- PV + row-sum: oacc += P @ Vt^T, lacc += P @ ones ----
    __builtin_amdgcn_s_setprio(1);
#pragma unroll
    for (int ks = 0; ks < 4; ++ks) {
      const bvec8 pb = __builtin_bit_cast(bvec8, pw[ks]);
      const int chunk = ks * 2 + hi;
#pragma unroll
      for (int dhb = 0; dhb < 2; ++dhb) {
        const int r = dhb * 32 + l31;
        bvec8 vf = *(const bvec8*)&Vs[buf][r * 128 + ((chunk ^ (r & 7)) << 4)];
        oacc[dhb] = MFMA32(pb, vf, oacc[dhb]);
      }
      lacc = MFMA32(pb, ones, lacc);   // all 32 cols identical = row sum
    }
    __builtin_amdgcn_s_setprio(0);
  }

  // ---- epilogue: unnormalized O + row sums ----
  bf16* pob = po + (size_t)half * 2097152;
#pragma unroll
  for (int dhb = 0; dhb < 2; ++dhb)
#pragma unroll
    for (int r2 = 0; r2 < 16; ++r2) {
      const int q = qw0 + (r2 & 3) + 8 * (r2 >> 2) + 4 * hi;
      pob[(size_t)(b * 2048 + q) * 512 + h * 64 + dhb * 32 + l31] =
          (bf16)oacc[dhb][r2];
    }
  if (l31 == 0) {
#pragma unroll
    for (int r2 = 0; r2 < 16; ++r2) {
      const int q = qw0 + (r2 & 3) + 8 * (r2 >> 2) + 4 * hi;
      pl[half * 32768 + (b * 2048 + q) * 8 + h] = lacc[r2];
    }
  }
}

// ---------------------------------------------------------------------------
// Combine 2 kv-halves: att = (O_0 + O_1) / (l_0 + l_1). 1024 blocks x 256.
// ---------------------------------------------------------------------------
__global__ void combine_kernel(const bf16* __restrict__ po, const float* __restrict__ pl,
                               bf16* __restrict__ att) {
  const int t = blockIdx.x * 256 + threadIdx.x;
  const int row = t >> 6;
  const int c8 = (t & 63) << 3;
  const int h = c8 >> 6;
  const float inv = 1.0f / (pl[row * 8 + h] + pl[32768 + row * 8 + h]);
  bvec8 a0 = *(const bvec8*)(po + (size_t)row * 512 + c8);
  bvec8 a1 = *(const bvec8*)(po + 2097152 + (size_t)row * 512 + c8);
  bvec8 o;
#pragma unroll
  for (int j = 0; j < 8; ++j)
    o[j] = (bf16)(((float)a0[j] + (float)a1[j]) * inv);
  *(bvec8*)(att + (size_t)row * 512 + c8) = o;
}

// ---------------------------------------------------------------------------
// Out GEMM: out = att @ Wc^T + bias (f32 out).
// ---------------------------------------------------------------------------
__launch_bounds__(256, 3)
__global__ void out_gemm(const bf16* __restrict__ X, const bf16* __restrict__ W,
                         const float* __restrict__ bias, float* __restrict__ Y) {
  __shared__ __attribute__((aligned(16))) char As[2][64 * 128];   // 8 KB each
  __shared__ __attribute__((aligned(16))) char Bs[2][128 * 128];  // 16 KB each

  const int tid = threadIdx.x;
  const int w = tid >> 6, l = tid & 63;
  const int wr = w >> 1, wc = w & 1;
  const int l15 = l & 15, lg = l >> 4;
  const int bm0 = blockIdx.x * 64;
  const int bn0 = blockIdx.y * 128;

  fvec4 acc[2][4] = {};

  auto stageA = [&](int buf, int k0) {
#pragma unroll
    for (int j = 0; j < 2; ++j) {
      int c = j * 256 + tid;
      int row = c >> 3, g = (c & 7) ^ (row & 7);
      async16(X + (size_t)(bm0 + row) * 512 + k0 + g * 8, &As[buf][c * 16]);
    }
  };
  auto stageB = [&](int buf, int k0) {
#pragma unroll
    for (int j = 0; j < 4; ++j) {
      int c = j * 256 + tid;
      int row = c >> 3, g = (c & 7) ^ (row & 7);
      async16(W + (size_t)(bn0 + row) * 512 + k0 + g * 8, &Bs[buf][c * 16]);
    }
  };

  stageA(0, 0);
  stageB(0, 0);
  __syncthreads();

  for (int t = 0; t < 8; ++t) {
    const int buf = t & 1;
    if (t < 7) { stageA(buf ^ 1, (t + 1) * 64); stageB(buf ^ 1, (t + 1) * 64); }
#pragma unroll
    for (int kk = 0; kk < 2; ++kk) {
      bvec8 af[2], bfr[4];
      const int g = kk * 4 + lg;
#pragma unroll
      for (int m = 0; m < 2; ++m) {
        int r = wr * 32 + m * 16 + l15;
        af[m] = *(const bvec8*)&As[buf][r * 128 + ((g ^ (r & 7)) << 4)];
      }
#pragma unroll
      for (int n = 0; n < 4; ++n) {
        int r = wc * 64 + n * 16 + l15;
        bfr[n] = *(const bvec8*)&Bs[buf][r * 128 + ((g ^ (r & 7)) << 4)];
      }
#pragma unroll
      for (int m = 0; m < 2; ++m)
#pragma unroll
        for (int n = 0; n < 4; ++n) acc[m][n] = MFMA16(af[m], bfr[n], acc[m][n]);
    }
    __syncthreads();
  }

#pragma unroll
  for (int n = 0; n < 4; ++n) {
    const int col = bn0 + wc * 64 + n * 16 + l15;
    const float bv = bias[col];
#pragma unroll
    for (int m = 0; m < 2; ++m) {
      const int row0 = bm0 + wr * 32 + m * 16 + lg * 4;
#pragma unroll
      for (int r = 0; r < 4; ++r)
        Y[(size_t)(row0 + r) * 512 + col] = acc[m][n][r] + bv;
    }
  }
}

// ---------------------------------------------------------------------------
extern "C" void kernel_launch(void* const* d_in, const int* in_sizes, int n_in,
                              void* d_out, int out_size, void* d_ws, size_t ws_size,
                              hipStream_t stream) {
  const float* q   = (const float*)d_in[0];
  const float* k   = (const float*)d_in[1];
  const float* v   = (const float*)d_in[2];
  const float* Wq  = (const float*)d_in[3];
  const float* Wqb = (const float*)d_in[4];
  const float* Wc  = (const float*)d_in[5];
  const float* Wcb = (const float*)d_in[6];
  float* out = (float*)d_out;

  char* ws = (char*)d_ws;
  const size_t MB = 1u << 20;
  bf16* qkvb = (bf16*)(ws);                        // [3][4096][512], 0..12MB
  bf16* po   = (bf16*)(ws);                        // [2][4096][512] reuses qkvb
  bf16* att  = (bf16*)(ws + 8 * MB);               // [4096][512], 8..12MB
  bf16* Wq16 = (bf16*)(ws + 12 * MB);              // 0.5MB
  bf16* Wc16 = (bf16*)(ws + 12 * MB + 512 * 1024); // 0.5MB
  bf16* qkp  = (bf16*)(ws + 13 * MB);              // [8192][512], 13..21MB
  bf16* vt   = (bf16*)(ws + 21 * MB);              // [b][h][dh][2048], 21..25MB
  float* pl  = (float*)(ws + 33 * MB);             // [2][4096][8] f32, 256KB

  dim3 bb(256);
  hipLaunchKernelGGL(cvt_all, dim3(3328), bb, 0, stream, q, k, v, Wq, Wc,
                     qkvb, Wq16, Wc16);
  hipLaunchKernelGGL(proj_gemm, dim3(192, 4), bb, 0, stream,
                     qkvb, Wq16, Wqb, qkp, vt);
  hipLaunchKernelGGL(attn_kernel, dim3(16, 16, 2), bb, 0, stream,
                     qkp, qkp + 2097152, vt, po, pl);
  hipLaunchKernelGGL(combine_kernel, dim3(1024), bb, 0, stream, po, pl, att);
  hipLaunchKernelGGL(out_gemm, dim3(64, 4), bb, 0, stream,
                     att, Wc16, Wcb, out);
}